// Round 3
// baseline (408.751 us; speedup 1.0000x reference)
//
#include <hip/hip_runtime.h>
#include <cstdint>
#include <cstddef>

constexpr int B = 64, N = 2048, E = 512, D = 256, H = 256, K = 5, I = 768;

__device__ __forceinline__ float sg(float x) { return 1.0f / (1.0f + __expf(-x)); }

__device__ __forceinline__ void dot4(float4 v, const float* s, float& acc) {
  acc += v.x * s[0];
  acc += v.y * s[1];
  acc += v.z * s[2];
  acc += v.w * s[3];
}

// One block (512 thr) per batch element.
// Waves 0-3: gi = x @ W_ih.T (x = [dec_z, 0] -> first 256 cols only).
// Waves 4-7: gh = h_prev @ W_hh.T.  Then GRU combine, K MLPs (half-dots
// split across the two thread halves), arg = mean/scale, and the
// truncated mixture-CDF contraction over enc_z.
__global__ __launch_bounds__(512) void fused(
    const float* __restrict__ enc, const float* __restrict__ dec,
    const float* __restrict__ h0,
    const float* __restrict__ Wih, const float* __restrict__ Whh,
    const float* __restrict__ bih, const float* __restrict__ bhh,
    const float* __restrict__ W1,  const float* __restrict__ b1,
    const float* __restrict__ W2,  const float* __restrict__ b2,
    float* __restrict__ out_c, float* __restrict__ out_h)
{
  __shared__ float xs[D], hs[H], hn[H], ghs[3][H];
  __shared__ float pl[K][H], pu[K][H], hid[K][H], pr[16];
  __shared__ float s_arg;
  const int b = blockIdx.x, t = threadIdx.x;
  if (t < D) xs[t] = dec[b * D + t];
  else       hs[t - D] = h0[b * H + (t - D)];
  __syncthreads();

  // --- GRU gate dots, split across thread halves (wave-uniform branch) ---
  const bool lo = t < H;          // waves 0-3
  const int  j  = t & (H - 1);
  const float* Wb   = lo ? Wih : Whh;
  const float* vec  = lo ? xs  : hs;
  const float* bias = lo ? bih : bhh;
  const size_t rs   = lo ? (size_t)I : (size_t)H;
  float gr = bias[j], gz = bias[H + j], gn = bias[2 * H + j];
  const float4* wr = reinterpret_cast<const float4*>(Wb + (size_t)j         * rs);
  const float4* wz = reinterpret_cast<const float4*>(Wb + (size_t)(H + j)   * rs);
  const float4* wn = reinterpret_cast<const float4*>(Wb + (size_t)(2*H + j) * rs);
#pragma unroll 8
  for (int c = 0; c < 64; ++c) {
    dot4(wr[c], &vec[c*4], gr);
    dot4(wz[c], &vec[c*4], gz);
    dot4(wn[c], &vec[c*4], gn);
  }
  if (!lo) { ghs[0][j] = gr; ghs[1][j] = gz; ghs[2][j] = gn; }
  __syncthreads();
  if (lo) {
    const float r  = sg(gr + ghs[0][j]);
    const float z  = sg(gz + ghs[1][j]);
    const float nn = tanhf(gn + r * ghs[2][j]);
    const float hnew = (1.0f - z) * nn + z * hs[j];
    hn[j] = hnew;
    out_h[b * H + j] = hnew;
  }
  __syncthreads();

  // --- K MLPs: hid[k][h] = tanh(W1[k,h,:] . h_new + b1[k,h]) ---
  // lo threads do elements 0..127 of row h=j, hi threads do 128..255.
  const float* hhalf = hn + (lo ? 0 : 128);
  float (*pp)[H] = lo ? pl : pu;
#pragma unroll
  for (int k = 0; k < K; ++k) {
    float acc = 0.0f;
    const float4* w = reinterpret_cast<const float4*>(
        W1 + ((size_t)k * H + j) * H + (lo ? 0 : 128));
#pragma unroll 8
    for (int c = 0; c < 32; ++c) dot4(w[c], &hhalf[c*4], acc);
    pp[k][j] = acc;
  }
  __syncthreads();
  if (lo) {
#pragma unroll
    for (int k = 0; k < K; ++k)
      hid[k][j] = tanhf(pl[k][j] + pu[k][j] + b1[k * H + j]);
  }
  __syncthreads();

  // --- params[k,p] = W2[k,p,:] . hid[k,:] + b2[k,p]; 15 dots, 16 thr each ---
  if (t < 240) {
    const int g = t >> 4, sub = t & 15;
    const int k = g / 3, p = g % 3;
    float s = 0.0f;
#pragma unroll
    for (int c = 0; c < 16; ++c) {
      const int h = sub + 16 * c;
      s += hid[k][h] * W2[(k * 3 + p) * H + h];
    }
    s += __shfl_xor(s, 8, 16);
    s += __shfl_xor(s, 4, 16);
    s += __shfl_xor(s, 2, 16);
    s += __shfl_xor(s, 1, 16);
    if (sub == 0) pr[g] = s + b2[k * 3 + p];
  }
  __syncthreads();

  // mean = exp(p0), scale = exp(p1) (only last component survives);
  // arg = mean/scale = exp(p0-p1). softmax weights sum to 1 -> drop out.
  if (t == 0) s_arg = __expf(pr[3 * (K - 1)] - pr[3 * (K - 1) + 1]);
  __syncthreads();

  // --- c[b,e] = sum_n (sig(n+.5-arg)-sig(n-.5-arg)) * enc[b,n,e] ---
  // a[n] ~ e^{-(n-arg)}: truncate at ceil(arg)+32 (tail < 1e-13 << 6.25e-2).
  const float arg = s_arg;
  const float lim = ceilf(arg) + 32.0f;
  int nmax = (lim < (float)N) ? (int)lim : N;  // also guards Inf/NaN arg
  if (nmax < 1) nmax = 1;

  const float* src = enc + (size_t)b * N * E + t;  // thread t owns column t
  float acc = 0.0f;
#pragma unroll 4
  for (int n = 0; n < nmax; ++n) {
    const float fn = (float)n;
    const float an = sg(fn + 0.5f - arg) - sg(fn - 0.5f - arg);
    acc += an * src[(size_t)n * E];
  }
  out_c[b * E + t] = acc;
}

extern "C" void kernel_launch(void* const* d_in, const int* in_sizes, int n_in,
                              void* d_out, int out_size, void* d_ws, size_t ws_size,
                              hipStream_t stream) {
  const float* enc = (const float*)d_in[0];
  const float* dec = (const float*)d_in[1];
  const float* h0  = (const float*)d_in[2];
  const float* Wih = (const float*)d_in[3];
  const float* Whh = (const float*)d_in[4];
  const float* bih = (const float*)d_in[5];
  const float* bhh = (const float*)d_in[6];
  const float* W1  = (const float*)d_in[7];
  const float* b1  = (const float*)d_in[8];
  const float* W2  = (const float*)d_in[9];
  const float* b2  = (const float*)d_in[10];
  (void)in_sizes; (void)n_in; (void)out_size; (void)d_ws; (void)ws_size;

  float* out_c = (float*)d_out;            // (1, B, E) first
  float* out_h = out_c + (size_t)B * E;    // then (1, B, H)

  hipLaunchKernelGGL(fused, dim3(B), dim3(512), 0, stream,
                     enc, dec, h0, Wih, Whh, bih, bhh, W1, b1, W2, b2,
                     out_c, out_h);
}